// Round 1
// baseline (1380.533 us; speedup 1.0000x reference)
//
#include <hip/hip_runtime.h>
#include <math.h>

// EGNN fused kernel, fp32 baseline.
// B=2, N=512, HD=64, U=128. One block per (b,i); j-tiles of 32.
// Four GEMV-chains per pair are done as 32x128 register-tiled GEMMs with
// transposed LDS staging ([k][j] layout, row pad 36 floats = 144B, 16B-aligned).

#define BB    2
#define NN    512
#define HDIM  64
#define UDIM  128
#define JT    32
#define NTILE (NN / JT)
#define RP    36   // padded row length in floats (144B, 16B-aligned rows)

__device__ __forceinline__ float eluf(float v) { return v > 0.f ? v : expm1f(v); }

__device__ __forceinline__ void fma4(float4& a, const float4 f, const float w) {
    a.x = fmaf(f.x, w, a.x); a.y = fmaf(f.y, w, a.y);
    a.z = fmaf(f.z, w, a.z); a.w = fmaf(f.w, w, a.w);
}
__device__ __forceinline__ void elu4(float4& a) {
    a.x = eluf(a.x); a.y = eluf(a.y); a.z = eluf(a.z); a.w = eluf(a.w);
}
// zero the component c where base+c == i (diagonal mask)
__device__ __forceinline__ void mask4(float4& a, int base, int i) {
    if (i == base + 0) a.x = 0.f;
    if (i == base + 1) a.y = 0.f;
    if (i == base + 2) a.z = 0.f;
    if (i == base + 3) a.w = 0.f;
}

// acc[j][u] += sum_k src[k][j] * W[k*128+u]   for j = goff..goff+15
template <int K>
__device__ __forceinline__ void gemm_tile(const float (*src)[RP], const float* __restrict__ W,
                                          const int u, const int goff,
                                          float4& a0, float4& a1, float4& a2, float4& a3) {
#pragma unroll 4
    for (int k = 0; k < K; ++k) {
        const float w = W[k * UDIM + u];
        const float4* fr = (const float4*)(&src[k][goff]);
        const float4 f0 = fr[0], f1 = fr[1], f2 = fr[2], f3 = fr[3];
        fma4(a0, f0, w); fma4(a1, f1, w); fma4(a2, f2, w); fma4(a3, f3, w);
    }
}

__device__ __forceinline__ void store_t(float (*dst)[RP], const int u, const int goff,
                                        const float4 a0, const float4 a1,
                                        const float4 a2, const float4 a3) {
    float4* d = (float4*)(&dst[u][goff]);
    d[0] = a0; d[1] = a1; d[2] = a2; d[3] = a3;
}

__global__ __launch_bounds__(256, 2) void egnn_fused(
    const float* __restrict__ x, const float* __restrict__ h,
    const float* __restrict__ We1, const float* __restrict__ be1,
    const float* __restrict__ We2, const float* __restrict__ be2,
    const float* __restrict__ Winf, const float* __restrict__ binf,
    const float* __restrict__ Wx1, const float* __restrict__ bx1,
    const float* __restrict__ Wx2, const float* __restrict__ bx2,
    const float* __restrict__ Wx3, const float* __restrict__ bx3,
    const float* __restrict__ Wh1, const float* __restrict__ bh1,
    const float* __restrict__ Wh2, const float* __restrict__ bh2,
    const float* __restrict__ Wout, const float* __restrict__ bout,
    float* __restrict__ out) {
    __shared__ float F[129][RP];     // featT: [k][j]   (rows 65..128 = h_i, tile-invariant)
    __shared__ float P1[128][RP];    // ping
    __shared__ float P2[128][RP];    // pong
    __shared__ float diffL[JT][3];
    __shared__ float eL[JT];
    __shared__ float phiL[JT];
    __shared__ float shiftL[3];
    __shared__ float miL[2][UDIM];
    __shared__ float catL[UDIM + HDIM];
    __shared__ float th1[UDIM];
    __shared__ float th2[UDIM];

    const int bi = blockIdx.x;           // 0..B*N-1
    const int b  = bi / NN;
    const int i  = bi % NN;
    const int tid  = threadIdx.x;
    const int u    = tid & (UDIM - 1);   // 0..127
    const int g    = tid >> 7;           // 0/1
    const int goff = g * 16;

    const float rbe1 = be1[u], rbe2 = be2[u], rbx1 = bx1[u], rbx2 = bx2[u];
    const float binf0 = binf[0], bx30 = bx3[0];

    const float xi0 = x[(b * NN + i) * 3 + 0];
    const float xi1 = x[(b * NN + i) * 3 + 1];
    const float xi2 = x[(b * NN + i) * 3 + 2];

    // constant rows of featT: F[65+k][j] = h_i[k] for all j
    for (int idx = tid; idx < HDIM * JT; idx += 256) {
        const int k = idx / JT, j = idx % JT;
        F[65 + k][j] = h[(b * NN + i) * HDIM + k];
    }
    if (tid == 0) { shiftL[0] = 0.f; shiftL[1] = 0.f; shiftL[2] = 0.f; }

    float mi_part = 0.f;

    for (int t = 0; t < NTILE; ++t) {
        const int j0 = t * JT;
        __syncthreads();  // protect diffL/F vs previous-tile readers

        // ---- build tile-varying part of featT + diff/norm ----
        if (tid < JT) {
            const int j = j0 + tid;
            float d0 = x[(b * NN + j) * 3 + 0] - xi0;
            float d1 = x[(b * NN + j) * 3 + 1] - xi1;
            float d2 = x[(b * NN + j) * 3 + 2] - xi2;
            if (j == i) { d0 = 0.f; d1 = 0.f; d2 = 0.f; }
            diffL[tid][0] = d0; diffL[tid][1] = d1; diffL[tid][2] = d2;
            const float sq = d0 * d0 + d1 * d1 + d2 * d2;
            F[0][tid] = (j == i) ? 0.f : sqrtf(sq);
        }
        for (int idx = tid; idx < HDIM * JT; idx += 256) {
            const int k = idx / JT, j = idx % JT;
            F[1 + k][j] = h[(b * NN + j0 + j) * HDIM + k];
        }
        __syncthreads();

        // ---- GEMM1: t1 = elu(feat @ We1 + be1) ----
        float4 a0 = {rbe1, rbe1, rbe1, rbe1}, a1 = a0, a2 = a0, a3 = a0;
        gemm_tile<129>(F, We1, u, goff, a0, a1, a2, a3);
        elu4(a0); elu4(a1); elu4(a2); elu4(a3);
        store_t(P1, u, goff, a0, a1, a2, a3);
        __syncthreads();

        // ---- GEMM2: m_ij = (t1 @ We2 + be2), diagonal-masked ----
        float4 m0 = {rbe2, rbe2, rbe2, rbe2}, m1 = m0, m2 = m0, m3 = m0;
        gemm_tile<128>(P1, We2, u, goff, m0, m1, m2, m3);
        mask4(m0, j0 + goff + 0, i); mask4(m1, j0 + goff + 4, i);
        mask4(m2, j0 + goff + 8, i); mask4(m3, j0 + goff + 12, i);
        store_t(P2, u, goff, m0, m1, m2, m3);
        __syncthreads();

        // ---- e = sigmoid(m_ij @ Winf + binf), masked ----
        if (tid < JT) {
            float s = 0.f;
            for (int k = 0; k < UDIM; ++k) s = fmaf(P2[k][tid], Winf[k], s);
            float e = 1.f / (1.f + expf(-(s + binf0)));
            if (j0 + tid == i) e = 0.f;
            eL[tid] = e;
        }
        __syncthreads();

        // ---- m_i partial accumulation (registers hold masked m_ij) ----
        {
            const float4 e0 = ((const float4*)&eL[goff])[0];
            const float4 e1 = ((const float4*)&eL[goff])[1];
            const float4 e2 = ((const float4*)&eL[goff])[2];
            const float4 e3 = ((const float4*)&eL[goff])[3];
            mi_part += m0.x * e0.x + m0.y * e0.y + m0.z * e0.z + m0.w * e0.w;
            mi_part += m1.x * e1.x + m1.y * e1.y + m1.z * e1.z + m1.w * e1.w;
            mi_part += m2.x * e2.x + m2.y * e2.y + m2.z * e2.z + m2.w * e2.w;
            mi_part += m3.x * e3.x + m3.y * e3.y + m3.z * e3.z + m3.w * e3.w;
        }

        // ---- GEMM3: h1 = elu(m_ij @ Wx1 + bx1) ----
        float4 q0 = {rbx1, rbx1, rbx1, rbx1}, q1 = q0, q2 = q0, q3 = q0;
        gemm_tile<128>(P2, Wx1, u, goff, q0, q1, q2, q3);
        elu4(q0); elu4(q1); elu4(q2); elu4(q3);
        __syncthreads();                 // P1's t1 is dead (GEMM2 done)
        store_t(P1, u, goff, q0, q1, q2, q3);
        __syncthreads();

        // ---- GEMM4: h2 = elu(h1 @ Wx2 + bx2) ----
        float4 r0 = {rbx2, rbx2, rbx2, rbx2}, r1 = r0, r2 = r0, r3 = r0;
        gemm_tile<128>(P1, Wx2, u, goff, r0, r1, r2, r3);
        elu4(r0); elu4(r1); elu4(r2); elu4(r3);
        __syncthreads();                 // P2's m_ij is dead (e-reduce + GEMM3 done)
        store_t(P2, u, goff, r0, r1, r2, r3);
        __syncthreads();

        // ---- phi = h2 @ Wx3 + bx3, masked; shift partial ----
        if (tid < JT) {
            float s = 0.f;
            for (int k = 0; k < UDIM; ++k) s = fmaf(P2[k][tid], Wx3[k], s);
            float p = s + bx30;
            if (j0 + tid == i) p = 0.f;
            phiL[tid] = p;
        }
        __syncthreads();
        if (tid < 3) {
            float s = 0.f;
            for (int j = 0; j < JT; ++j) s = fmaf(diffL[j][tid], phiL[j], s);
            shiftL[tid] += s;
        }
    }

    // ---- combine m_i halves ----
    miL[g][u] = mi_part;
    __syncthreads();
    if (tid < UDIM) catL[tid] = miL[0][tid] + miL[1][tid];
    if (tid >= 128 && tid < 128 + HDIM) catL[UDIM + (tid - 128)] = h[(b * NN + i) * HDIM + (tid - 128)];
    __syncthreads();

    // ---- h-MLP epilogue: h_new = (elu(cat@Wh1+bh1)@Wh2+bh2)@Wout + bout ----
    if (tid < UDIM) {
        float s = bh1[tid];
        for (int k = 0; k < UDIM + HDIM; ++k) s = fmaf(catL[k], Wh1[k * UDIM + tid], s);
        th1[tid] = eluf(s);
    }
    __syncthreads();
    if (tid < UDIM) {
        float s = bh2[tid];
        for (int k = 0; k < UDIM; ++k) s = fmaf(th1[k], Wh2[k * UDIM + tid], s);
        th2[tid] = s;
    }
    __syncthreads();
    if (tid < HDIM) {
        float s = bout[tid];
        for (int k = 0; k < UDIM; ++k) s = fmaf(th2[k], Wout[k * HDIM + tid], s);
        out[BB * NN * 3 + (b * NN + i) * HDIM + tid] = s;
    }
    if (tid < 3) {
        out[(b * NN + i) * 3 + tid] = x[(b * NN + i) * 3 + tid] + shiftL[tid] / (float)(NN - 1);
    }
}

extern "C" void kernel_launch(void* const* d_in, const int* in_sizes, int n_in,
                              void* d_out, int out_size, void* d_ws, size_t ws_size,
                              hipStream_t stream) {
    const float* x    = (const float*)d_in[0];
    const float* h    = (const float*)d_in[1];
    const float* We1  = (const float*)d_in[2];
    const float* be1  = (const float*)d_in[3];
    const float* We2  = (const float*)d_in[4];
    const float* be2  = (const float*)d_in[5];
    const float* Winf = (const float*)d_in[6];
    const float* binf = (const float*)d_in[7];
    const float* Wx1  = (const float*)d_in[8];
    const float* bx1  = (const float*)d_in[9];
    const float* Wx2  = (const float*)d_in[10];
    const float* bx2  = (const float*)d_in[11];
    const float* Wx3  = (const float*)d_in[12];
    const float* bx3  = (const float*)d_in[13];
    const float* Wh1  = (const float*)d_in[14];
    const float* bh1  = (const float*)d_in[15];
    const float* Wh2  = (const float*)d_in[16];
    const float* bh2  = (const float*)d_in[17];
    const float* Wout = (const float*)d_in[18];
    const float* bout = (const float*)d_in[19];
    float* out = (float*)d_out;

    hipLaunchKernelGGL(egnn_fused, dim3(BB * NN), dim3(256), 0, stream,
                       x, h, We1, be1, We2, be2, Winf, binf, Wx1, bx1, Wx2, bx2,
                       Wx3, bx3, Wh1, bh1, Wh2, bh2, Wout, bout, out);
}

// Round 2
// 158.902 us; speedup vs baseline: 8.6879x; 8.6879x over previous
//
#include <hip/hip_runtime.h>
#include <math.h>

// EGNN fused kernel, round 2: bf16 MFMA for the 4 pairwise GEMMs.
// B=2, N=512, HD=64, U=128. One block (256 thr, 4 waves) per (b,i); j-tiles of 32.
// Wave w owns u in [32w,32w+32). mfma_f32_16x16x32_bf16, fragments:
//   A: row=lane&15, k=(lane>>4)*8+i ; B: k=(lane>>4)*8+i, col=lane&15
//   C/D: col=lane&15, row=(lane>>4)*4+r   [guide m89]
// feat@We1 = norm (x) We1[0]  (exact fp32 rank-1)  +  h_j@We1[1:65] (MFMA K=64)
//            + h_i@We1[65:129] (per-block bias, fp32)

#define BB    2
#define NN    512
#define HDIM  64
#define UDIM  128
#define JT    32
#define NTILE (NN / JT)
#define FP    72    // F row pitch (ushort), 144B = 9*16B
#define PP    136   // P row pitch (ushort), 272B = 17*16B

typedef float f32x4 __attribute__((ext_vector_type(4)));
typedef short s16x8 __attribute__((ext_vector_type(8)));

__device__ __forceinline__ ushort f2bf(float f) {
    union { float f; unsigned u; } v; v.f = f;
    return (ushort)((v.u + 0x7FFFu + ((v.u >> 16) & 1u)) >> 16);  // RNE
}
__device__ __forceinline__ float bf2f(ushort s) {
    union { unsigned u; float f; } v; v.u = ((unsigned)s) << 16; return v.f;
}
__device__ __forceinline__ f32x4 MFMA(s16x8 a, s16x8 b, f32x4 c) {
    return __builtin_amdgcn_mfma_f32_16x16x32_bf16(a, b, c, 0, 0, 0);
}
__device__ __forceinline__ float eluf(float v) { return v > 0.f ? v : __expf(v) - 1.f; }

// B-fragment gather: dst[s][n] holds W[32s+8q+i][ucol+16n], i=0..7 (bf16)
__device__ __forceinline__ void load_wfrags(const float* __restrict__ W, int q, int ucol,
                                            s16x8 (&dst)[4][2]) {
#pragma unroll
    for (int s = 0; s < 4; ++s)
#pragma unroll
        for (int n = 0; n < 2; ++n) {
            s16x8 r;
#pragma unroll
            for (int ii = 0; ii < 8; ++ii)
                r[ii] = (short)f2bf(W[(32 * s + 8 * q + ii) * UDIM + ucol + 16 * n]);
            dst[s][n] = r;
        }
}

// acc[m][n] += A(P)[16m+.., k] * wB ; A rows via l15, k via q
template <int KSTEPS, int PITCH>
__device__ __forceinline__ void gemm_P(const ushort* __restrict__ P, const s16x8 (&wB)[KSTEPS][2],
                                       int l15, int q, f32x4 (&acc)[2][2]) {
#pragma unroll
    for (int s = 0; s < KSTEPS; ++s) {
        const s16x8 a0 = *(const s16x8*)(P + l15 * PITCH + 32 * s + 8 * q);
        const s16x8 a1 = *(const s16x8*)(P + (16 + l15) * PITCH + 32 * s + 8 * q);
        acc[0][0] = MFMA(a0, wB[s][0], acc[0][0]);
        acc[0][1] = MFMA(a0, wB[s][1], acc[0][1]);
        acc[1][0] = MFMA(a1, wB[s][0], acc[1][0]);
        acc[1][1] = MFMA(a1, wB[s][1], acc[1][1]);
    }
}

template <bool ELU>
__device__ __forceinline__ void store_P(ushort* __restrict__ P, const f32x4 (&v)[2][2],
                                        int q, int uc0, int uc1) {
#pragma unroll
    for (int m = 0; m < 2; ++m)
#pragma unroll
        for (int r = 0; r < 4; ++r) {
            const int row = 16 * m + 4 * q + r;
            float a = v[m][0][r], c = v[m][1][r];
            if (ELU) { a = eluf(a); c = eluf(c); }
            P[row * PP + uc0] = f2bf(a);
            P[row * PP + uc1] = f2bf(c);
        }
}

__global__ __launch_bounds__(256, 2) void egnn_mfma(
    const float* __restrict__ x, const float* __restrict__ h,
    const float* __restrict__ We1, const float* __restrict__ be1,
    const float* __restrict__ We2, const float* __restrict__ be2,
    const float* __restrict__ Winf, const float* __restrict__ binf,
    const float* __restrict__ Wx1, const float* __restrict__ bx1,
    const float* __restrict__ Wx2, const float* __restrict__ bx2,
    const float* __restrict__ Wx3, const float* __restrict__ bx3,
    const float* __restrict__ Wh1, const float* __restrict__ bh1,
    const float* __restrict__ Wh2, const float* __restrict__ bh2,
    const float* __restrict__ Wout, const float* __restrict__ bout,
    float* __restrict__ out) {
    __shared__ ushort F[JT][FP];      // h_j tile, bf16, [j][k]
    __shared__ ushort P1[JT][PP];     // ping (t1 / h1), bf16, [j][u]
    __shared__ ushort P2[JT][PP];     // pong (m_ij / h2)
    __shared__ float normL[JT];
    __shared__ float diffL[JT][3];
    __shared__ float rpart[8][JT];    // e/phi dot partials
    __shared__ float eL[JT];
    __shared__ float bias1L[UDIM];
    __shared__ float WinfL[UDIM], Wx3L[UDIM];
    __shared__ float catL[UDIM + HDIM];
    __shared__ float th1[UDIM], th2[UDIM];

    const int bi = blockIdx.x;
    const int b  = bi >> 9;          // / NN
    const int i  = bi & (NN - 1);
    const int tid  = threadIdx.x;
    const int lane = tid & 63;
    const int w    = tid >> 6;       // wave id: u block [32w, 32w+32)
    const int l15  = lane & 15;
    const int q    = lane >> 4;
    const int uc0  = 32 * w + l15, uc1 = uc0 + 16;

    // ---- per-block setup ----
    s16x8 wB1[2][2];                 // We1 rows 1..64 (h_j part), K=64
#pragma unroll
    for (int s = 0; s < 2; ++s)
#pragma unroll
        for (int n = 0; n < 2; ++n) {
            s16x8 r;
#pragma unroll
            for (int ii = 0; ii < 8; ++ii)
                r[ii] = (short)f2bf(We1[(1 + 32 * s + 8 * q + ii) * UDIM + uc0 + 16 * n]);
            wB1[s][n] = r;
        }
    s16x8 wB2[4][2], wB3[4][2], wB4[4][2];
    load_wfrags(We2, q, uc0, wB2);
    load_wfrags(Wx1, q, uc0, wB3);
    load_wfrags(Wx2, q, uc0, wB4);

    if (tid < UDIM) {
        WinfL[tid] = Winf[tid];
        Wx3L[tid]  = Wx3[tid];
        float s = be1[tid];
        const float* hi = &h[(b * NN + i) * HDIM];
#pragma unroll 8
        for (int k = 0; k < HDIM; ++k)
            s = fmaf(hi[k], We1[(1 + HDIM + k) * UDIM + tid], s);
        bias1L[tid] = s;             // be1 + h_i @ We1[65:129]
    }
    const float w0n0 = We1[uc0], w0n1 = We1[uc1];          // We1 row 0 (norm)
    const float b2n0 = be2[uc0], b2n1 = be2[uc1];
    const float bqn0 = bx1[uc0], bqn1 = bx1[uc1];
    const float brn0 = bx2[uc0], brn1 = bx2[uc1];
    const float binf0 = binf[0], bx30 = bx3[0];
    const float xi0 = x[(b * NN + i) * 3 + 0];
    const float xi1 = x[(b * NN + i) * 3 + 1];
    const float xi2 = x[(b * NN + i) * 3 + 2];
    __syncthreads();
    const float b1n0 = bias1L[uc0], b1n1 = bias1L[uc1];

    float mi0 = 0.f, mi1 = 0.f;          // m_i accumulators (u = uc0, uc1)
    float sh0 = 0.f, sh1 = 0.f, sh2 = 0.f;  // shift accumulator (wave 0)

    for (int t = 0; t < NTILE; ++t) {
        const int j0 = t * JT;
        __syncthreads();  // (A)

        // ---- stage h_j -> F (bf16), diffs/norms ----
        {
            const int j = tid >> 3, k0 = (tid & 7) * 8;
            const float* hp = &h[(b * NN + j0 + j) * HDIM + k0];
            const float4 f0 = *(const float4*)hp;
            const float4 f1 = *(const float4*)(hp + 4);
            s16x8 r;
            r[0] = (short)f2bf(f0.x); r[1] = (short)f2bf(f0.y);
            r[2] = (short)f2bf(f0.z); r[3] = (short)f2bf(f0.w);
            r[4] = (short)f2bf(f1.x); r[5] = (short)f2bf(f1.y);
            r[6] = (short)f2bf(f1.z); r[7] = (short)f2bf(f1.w);
            *(s16x8*)&F[j][k0] = r;
        }
        if (tid < JT) {
            const int j = j0 + tid;
            float d0 = x[(b * NN + j) * 3 + 0] - xi0;
            float d1 = x[(b * NN + j) * 3 + 1] - xi1;
            float d2 = x[(b * NN + j) * 3 + 2] - xi2;
            if (j == i) { d0 = 0.f; d1 = 0.f; d2 = 0.f; }
            diffL[tid][0] = d0; diffL[tid][1] = d1; diffL[tid][2] = d2;
            normL[tid] = (j == i) ? 0.f : sqrtf(d0 * d0 + d1 * d1 + d2 * d2);
        }
        __syncthreads();  // (B)

        // ---- GEMM1: t1 = elu(norm*We1r0 + h_j@We1[1:65] + bias1) ----
        float nrm[2][4];
#pragma unroll
        for (int m = 0; m < 2; ++m)
#pragma unroll
            for (int r = 0; r < 4; ++r) nrm[m][r] = normL[16 * m + 4 * q + r];
        f32x4 acc[2][2];
#pragma unroll
        for (int m = 0; m < 2; ++m)
#pragma unroll
            for (int r = 0; r < 4; ++r) {
                acc[m][0][r] = fmaf(nrm[m][r], w0n0, b1n0);
                acc[m][1][r] = fmaf(nrm[m][r], w0n1, b1n1);
            }
        gemm_P<2, FP>(&F[0][0], wB1, l15, q, acc);
        store_P<true>(&P1[0][0], acc, q, uc0, uc1);
        __syncthreads();  // (C)

        // ---- GEMM2: m_ij = t1@We2 + be2, diagonal-masked ----
        f32x4 macc[2][2];
#pragma unroll
        for (int m = 0; m < 2; ++m)
#pragma unroll
            for (int r = 0; r < 4; ++r) { macc[m][0][r] = b2n0; macc[m][1][r] = b2n1; }
        gemm_P<4, PP>(&P1[0][0], wB2, l15, q, macc);
#pragma unroll
        for (int m = 0; m < 2; ++m)
#pragma unroll
            for (int r = 0; r < 4; ++r)
                if (j0 + 16 * m + 4 * q + r == i) { macc[m][0][r] = 0.f; macc[m][1][r] = 0.f; }
        store_P<false>(&P2[0][0], macc, q, uc0, uc1);
        __syncthreads();  // (D)

        // ---- e partials (all threads) + GEMM3: h1 = elu(m_ij@Wx1+bx1) ----
        {
            const int j = tid & 31, uch = tid >> 5, u0 = uch * 16;
            const s16x8 m0 = *(const s16x8*)&P2[j][u0];
            const s16x8 m1 = *(const s16x8*)&P2[j][u0 + 8];
            float p = 0.f;
#pragma unroll
            for (int c = 0; c < 8; ++c) p = fmaf(bf2f((ushort)m0[c]), WinfL[u0 + c], p);
#pragma unroll
            for (int c = 0; c < 8; ++c) p = fmaf(bf2f((ushort)m1[c]), WinfL[u0 + 8 + c], p);
            rpart[uch][j] = p;
        }
        f32x4 qacc[2][2];
#pragma unroll
        for (int m = 0; m < 2; ++m)
#pragma unroll
            for (int r = 0; r < 4; ++r) { qacc[m][0][r] = bqn0; qacc[m][1][r] = bqn1; }
        gemm_P<4, PP>(&P2[0][0], wB3, l15, q, qacc);
        store_P<true>(&P1[0][0], qacc, q, uc0, uc1);   // P1 free (GEMM2 reads done pre-D)
        __syncthreads();  // (E)

        // ---- e final (wave0 lanes<32) ; GEMM4: h2 = elu(h1@Wx2+bx2) ----
        if (tid < 32) {
            float s = 0.f;
#pragma unroll
            for (int p = 0; p < 8; ++p) s += rpart[p][tid];
            float e = 1.f / (1.f + __expf(-(s + binf0)));
            if (j0 + tid == i) e = 0.f;
            eL[tid] = e;
        }
        f32x4 racc[2][2];
#pragma unroll
        for (int m = 0; m < 2; ++m)
#pragma unroll
            for (int r = 0; r < 4; ++r) { racc[m][0][r] = brn0; racc[m][1][r] = brn1; }
        gemm_P<4, PP>(&P1[0][0], wB4, l15, q, racc);
        store_P<true>(&P2[0][0], racc, q, uc0, uc1);   // P2 free (readers done pre-E)
        __syncthreads();  // (F)

        // ---- phi partials ; m_i accumulation (fp32 register m_ij x eL) ----
        {
            const int j = tid & 31, uch = tid >> 5, u0 = uch * 16;
            const s16x8 m0 = *(const s16x8*)&P2[j][u0];
            const s16x8 m1 = *(const s16x8*)&P2[j][u0 + 8];
            float p = 0.f;
#pragma unroll
            for (int c = 0; c < 8; ++c) p = fmaf(bf2f((ushort)m0[c]), Wx3L[u0 + c], p);
#pragma unroll
            for (int c = 0; c < 8; ++c) p = fmaf(bf2f((ushort)m1[c]), Wx3L[u0 + 8 + c], p);
            rpart[uch][j] = p;
        }
        {
            float el[2][4];
#pragma unroll
            for (int m = 0; m < 2; ++m)
#pragma unroll
                for (int r = 0; r < 4; ++r) el[m][r] = eL[16 * m + 4 * q + r];
#pragma unroll
            for (int m = 0; m < 2; ++m)
#pragma unroll
                for (int r = 0; r < 4; ++r) {
                    mi0 = fmaf(macc[m][0][r], el[m][r], mi0);
                    mi1 = fmaf(macc[m][1][r], el[m][r], mi1);
                }
        }
        __syncthreads();  // (G)

        // ---- phi final + shift accumulation (wave 0, butterfly reduce) ----
        if (tid < 64) {
            const int l = tid & 31;
            float s = 0.f;
#pragma unroll
            for (int p = 0; p < 8; ++p) s += rpart[p][l];
            s += bx30;
            if (j0 + l == i) s = 0.f;
            float v0 = 0.f, v1 = 0.f, v2 = 0.f;
            if (tid < 32) {
                v0 = diffL[l][0] * s; v1 = diffL[l][1] * s; v2 = diffL[l][2] * s;
            }
#pragma unroll
            for (int d = 1; d < 64; d <<= 1) {
                v0 += __shfl_xor(v0, d);
                v1 += __shfl_xor(v1, d);
                v2 += __shfl_xor(v2, d);
            }
            sh0 += v0; sh1 += v1; sh2 += v2;
        }
    }

    __syncthreads();
    // ---- m_i cross-quarter reduce -> catL ----
    {
        float v0 = mi0, v1 = mi1;
        v0 += __shfl_xor(v0, 16); v0 += __shfl_xor(v0, 32);
        v1 += __shfl_xor(v1, 16); v1 += __shfl_xor(v1, 32);
        if (lane < 16) {
            catL[32 * w + lane]      = v0;
            catL[32 * w + 16 + lane] = v1;
        }
    }
    if (tid >= 128 && tid < 128 + HDIM)
        catL[UDIM + tid - 128] = h[(b * NN + i) * HDIM + (tid - 128)];
    if (tid == 0) {
        const float inv = 1.f / (float)(NN - 1);
        out[(b * NN + i) * 3 + 0] = x[(b * NN + i) * 3 + 0] + sh0 * inv;
        out[(b * NN + i) * 3 + 1] = x[(b * NN + i) * 3 + 1] + sh1 * inv;
        out[(b * NN + i) * 3 + 2] = x[(b * NN + i) * 3 + 2] + sh2 * inv;
    }
    __syncthreads();

    // ---- h-MLP epilogue (fp32) ----
    if (tid < UDIM) {
        float s = bh1[tid];
        for (int k = 0; k < UDIM + HDIM; ++k) s = fmaf(catL[k], Wh1[k * UDIM + tid], s);
        th1[tid] = eluf(s);
    }
    __syncthreads();
    if (tid < UDIM) {
        float s = bh2[tid];
        for (int k = 0; k < UDIM; ++k) s = fmaf(th1[k], Wh2[k * UDIM + tid], s);
        th2[tid] = s;
    }
    __syncthreads();
    if (tid < HDIM) {
        float s = bout[tid];
        for (int k = 0; k < UDIM; ++k) s = fmaf(th2[k], Wout[k * HDIM + tid], s);
        out[BB * NN * 3 + (b * NN + i) * HDIM + tid] = s;
    }
}

extern "C" void kernel_launch(void* const* d_in, const int* in_sizes, int n_in,
                              void* d_out, int out_size, void* d_ws, size_t ws_size,
                              hipStream_t stream) {
    const float* x    = (const float*)d_in[0];
    const float* h    = (const float*)d_in[1];
    const float* We1  = (const float*)d_in[2];
    const float* be1  = (const float*)d_in[3];
    const float* We2  = (const float*)d_in[4];
    const float* be2  = (const float*)d_in[5];
    const float* Winf = (const float*)d_in[6];
    const float* binf = (const float*)d_in[7];
    const float* Wx1  = (const float*)d_in[8];
    const float* bx1  = (const float*)d_in[9];
    const float* Wx2  = (const float*)d_in[10];
    const float* bx2  = (const float*)d_in[11];
    const float* Wx3  = (const float*)d_in[12];
    const float* bx3  = (const float*)d_in[13];
    const float* Wh1  = (const float*)d_in[14];
    const float* bh1  = (const float*)d_in[15];
    const float* Wh2  = (const float*)d_in[16];
    const float* bh2  = (const float*)d_in[17];
    const float* Wout = (const float*)d_in[18];
    const float* bout = (const float*)d_in[19];
    float* out = (float*)d_out;

    hipLaunchKernelGGL(egnn_mfma, dim3(BB * NN), dim3(256), 0, stream,
                       x, h, We1, be1, We2, be2, Winf, binf, Wx1, bx1, Wx2, bx2,
                       Wx3, bx3, Wh1, bh1, Wh2, bh2, Wout, bout, out);
}